// Round 3
// baseline (398.924 us; speedup 1.0000x reference)
//
#include <hip/hip_runtime.h>

// Problem constants: images (16,3,768,768) f32, h=w=48, N=2304,
// SIGMA_COLOR=0.1 -> exp(-50*cd), SIGMA_SPATIAL=5 -> exp(-0.02*sd), RADIUS=8.
#define BATCH 16
#define CH    3
#define HIN   768
#define WIN   768
#define HS    48
#define WS    48
#define NPIX  (HS * WS)          // 2304
#define QPR   (NPIX / 4)         // 576 float4 quads per output row

// Kernel 1: bilinear downsample 768->48 (half-pixel centers, scale 16).
// Output coord for index i is 16*i + 7.5 -> exact average of pixels {16i+7, 16i+8}
// in each axis, i.e. a 2x2 average. One thread per (b, n); writes float4 (c0,c1,c2,0).
__global__ void downsample_kernel(const float* __restrict__ img,
                                  float4* __restrict__ feats) {
    int idx = blockIdx.x * blockDim.x + threadIdx.x;   // over BATCH*NPIX = 36864
    if (idx >= BATCH * NPIX) return;
    int b = idx / NPIX;
    int n = idx - b * NPIX;
    int y = n / WS;
    int x = n - y * WS;
    int iy = 16 * y + 7;
    int ix = 16 * x + 7;
    const float* base = img + (size_t)b * CH * HIN * WIN;
    float f[3];
#pragma unroll
    for (int c = 0; c < 3; ++c) {
        const float* p = base + (size_t)c * HIN * WIN;
        const float* r0 = p + (size_t)iy * WIN + ix;
        const float* r1 = r0 + WIN;
        f[c] = 0.25f * (r0[0] + r0[1] + r1[0] + r1[1]);
    }
    feats[idx] = make_float4(f[0], f[1], f[2], 0.0f);
}

// Kernel 2: one block per (b, yi) = 768 blocks (3/CU), 576 threads.
// Thread (xq, yj) owns the float4 quad [yj*48 + 4*xq .. +3] of the j-axis and
// keeps it across ALL 48 i-rows sharing this yi (i = yi*48 + xi, xi = 0..47).
//
// Rounds 0 and 2 both ran ~170 us with wildly different per-thread code ->
// the limit was wave-LAUNCH rate (331,776 single-store waves; ~30-40 cyc/wave
// launch over 32 SEs ~= 150 us). This version has 6,912 waves, each doing 48
// float4 stores (the rocclr fill that hits 6.36 TB/s does ~160 stores/wave
// with 8,192 waves).
//
// Extra wins from putting yi in blockIdx:
//  - dy = yi - yj is THREAD-INVARIANT -> zero/active branch hoisted out of
//    the xi loop entirely; zero threads are a pure 48-store stream.
//  - fj quads are loop-invariant -> 4 float4 loads total, held in VGPRs.
//  - block writes one contiguous 442 KB span, full cache lines, once.
__global__ __launch_bounds__(576) void row_affinity_kernel(const float4* __restrict__ feats,
                                                           float4* __restrict__ out) {
    int yi = blockIdx.x;              // 0..47, block-uniform
    int b  = blockIdx.y;              // 0..15
    int xq = threadIdx.x;             // 0..11  (quad within j-row)
    int yj = threadIdx.y;             // 0..47  (j-row)
    int dy = yi - yj;                 // thread-invariant across the xi loop

    const float4* frow = feats + (size_t)b * NPIX;
    // this thread's store slot in row (b, i= yi*48 + 0), advanced by QPR per xi
    float4* oquad = out + ((size_t)b * NPIX + (size_t)yi * WS) * QPR + yj * 12 + xq;

    if (dy > 8 || dy < -8) {
        const float4 z = make_float4(0.f, 0.f, 0.f, 0.f);
#pragma unroll 4
        for (int xi = 0; xi < WS; ++xi) {
            oquad[(size_t)xi * QPR] = z;
        }
    } else {
        int xj0 = xq * 4;
        int j0  = yj * WS + xj0;
        float4 fj[4];
#pragma unroll
        for (int k = 0; k < 4; ++k) fj[k] = frow[j0 + k];
        float sdy = (float)(dy * dy);
        int ibase = yi * WS;
#pragma unroll 2
        for (int xi = 0; xi < WS; ++xi) {
            float4 fi = frow[ibase + xi];     // wave-uniform address -> s_load/broadcast
            float v[4];
#pragma unroll
            for (int k = 0; k < 4; ++k) {
                int dx = xi - (xj0 + k);
                float d0 = fi.x - fj[k].x;
                float d1 = fi.y - fj[k].y;
                float d2 = fi.z - fj[k].z;
                float cd = d0 * d0 + d1 * d1 + d2 * d2;
                float sd = sdy + (float)(dx * dx);
                float e  = __expf(-50.0f * cd - 0.02f * sd);
                v[k] = (dx > 8 || dx < -8) ? 0.0f : e;
            }
            oquad[(size_t)xi * QPR] = make_float4(v[0], v[1], v[2], v[3]);
        }
    }
}

extern "C" void kernel_launch(void* const* d_in, const int* in_sizes, int n_in,
                              void* d_out, int out_size, void* d_ws, size_t ws_size,
                              hipStream_t stream) {
    const float* img = (const float*)d_in[0];
    float4* feats = (float4*)d_ws;                 // 16*2304*16 B = 589,824 B
    float4* out4  = (float4*)d_out;                // 16*2304*2304 floats

    {
        int threads = BATCH * NPIX;                // 36,864
        int block = 256;
        int grid = (threads + block - 1) / block;  // 144
        downsample_kernel<<<grid, block, 0, stream>>>(img, feats);
    }
    {
        dim3 grid(HS, BATCH);                      // 48 x 16 = 768 blocks, 3/CU
        dim3 block(12, 48);                        // 576 threads = 9 waves
        row_affinity_kernel<<<grid, block, 0, stream>>>(feats, out4);
    }
}

// Round 4
// 394.861 us; speedup vs baseline: 1.0103x; 1.0103x over previous
//
#include <hip/hip_runtime.h>

// Problem constants: images (16,3,768,768) f32, h=w=48, N=2304,
// SIGMA_COLOR=0.1 -> exp(-50*cd), SIGMA_SPATIAL=5 -> exp(-0.02*sd), RADIUS=8.
#define BATCH 16
#define CH    3
#define HIN   768
#define WIN   768
#define HS    48
#define WS    48
#define NPIX  (HS * WS)          // 2304
#define QPR   (NPIX / 4)         // 576 float4 quads per output row

// Kernel 1: bilinear downsample 768->48 (half-pixel centers, scale 16).
// Output coord for index i is 16*i + 7.5 -> exact average of pixels {16i+7, 16i+8}
// in each axis, i.e. a 2x2 average. One thread per (b, n); writes float4 (c0,c1,c2,0).
__global__ void downsample_kernel(const float* __restrict__ img,
                                  float4* __restrict__ feats) {
    int idx = blockIdx.x * blockDim.x + threadIdx.x;   // over BATCH*NPIX = 36864
    if (idx >= BATCH * NPIX) return;
    int b = idx / NPIX;
    int n = idx - b * NPIX;
    int y = n / WS;
    int x = n - y * WS;
    int iy = 16 * y + 7;
    int ix = 16 * x + 7;
    const float* base = img + (size_t)b * CH * HIN * WIN;
    float f[3];
#pragma unroll
    for (int c = 0; c < 3; ++c) {
        const float* p = base + (size_t)c * HIN * WIN;
        const float* r0 = p + (size_t)iy * WIN + ix;
        const float* r1 = r0 + WIN;
        f[c] = 0.25f * (r0[0] + r0[1] + r1[0] + r1[1]);
    }
    feats[idx] = make_float4(f[0], f[1], f[2], 0.0f);
}

// Kernel 2 (v4, discriminator): round-3 geometry -- one block per (b, yi),
// 576 threads, thread (xq, yj) keeps its j-quad across all 48 xi -- but with
// a SINGLE store site at the branch-reconvergence point. Rounds 0-3 showed
// kernel-side time is pinned at ~165 us regardless of thread decomposition;
// the only remaining kernel-side suspect is the store stream: round 3 had
// two store sites under complementary exec masks (straddling waves issue
// partial-line stores -> read-for-ownership traffic). Here EVERY store is a
// full-exec, full-line 1 KB wave store, the block sweeps one contiguous
// 442 KB span, and fully-out-of-range waves still skip all compute via the
// (wave-uniform) branch.
// Pre-committed read: dur_us <= ~310 -> store-RFO theory right; ~385-400
// unchanged -> the residual is a harness floor (poison 213 + resets ~110 +
// write roofline 54) and we are at the roofline.
__global__ __launch_bounds__(576) void row_affinity_kernel(const float4* __restrict__ feats,
                                                           float4* __restrict__ out) {
    int yi = blockIdx.x;              // 0..47, block-uniform
    int b  = blockIdx.y;              // 0..15
    int xq = threadIdx.x;             // 0..11  (quad within j-row)
    int yj = threadIdx.y;             // 0..47  (j-row)
    int dy = yi - yj;                 // thread-invariant across the xi loop
    bool in_dy = (dy <= 8) && (dy >= -8);

    const float4* frow = feats + (size_t)b * NPIX;
    float4* oquad = out + ((size_t)b * NPIX + (size_t)yi * WS) * QPR + yj * 12 + xq;

    // fj quads are loop-invariant; load under the dy mask (exec-masked loads).
    int xj0 = xq * 4;
    float4 fj0, fj1, fj2, fj3;
    float sdy = (float)(dy * dy);
    if (in_dy) {
        int j0 = yj * WS + xj0;
        fj0 = frow[j0 + 0];
        fj1 = frow[j0 + 1];
        fj2 = frow[j0 + 2];
        fj3 = frow[j0 + 3];
    }

    int ibase = yi * WS;
#pragma unroll 4
    for (int xi = 0; xi < WS; ++xi) {
        float4 res = make_float4(0.f, 0.f, 0.f, 0.f);
        if (in_dy) {                   // uniform-false for ~5 of 9 waves
            float4 fi = frow[ibase + xi];   // wave-uniform address
            float v[4];
            float4 fj[4] = {fj0, fj1, fj2, fj3};
#pragma unroll
            for (int k = 0; k < 4; ++k) {
                int dx = xi - (xj0 + k);
                float d0 = fi.x - fj[k].x;
                float d1 = fi.y - fj[k].y;
                float d2 = fi.z - fj[k].z;
                float cd = d0 * d0 + d1 * d1 + d2 * d2;
                float sd = sdy + (float)(dx * dx);
                float e  = __expf(-50.0f * cd - 0.02f * sd);
                v[k] = (dx > 8 || dx < -8) ? 0.0f : e;
            }
            res = make_float4(v[0], v[1], v[2], v[3]);
        }
        *oquad = res;                  // single store site: full-exec, full-line
        oquad += QPR;                  // pointer bump, no per-iter 64-bit mul
    }
}

extern "C" void kernel_launch(void* const* d_in, const int* in_sizes, int n_in,
                              void* d_out, int out_size, void* d_ws, size_t ws_size,
                              hipStream_t stream) {
    const float* img = (const float*)d_in[0];
    float4* feats = (float4*)d_ws;                 // 16*2304*16 B = 589,824 B
    float4* out4  = (float4*)d_out;                // 16*2304*2304 floats

    {
        int threads = BATCH * NPIX;                // 36,864
        int block = 256;
        int grid = (threads + block - 1) / block;  // 144
        downsample_kernel<<<grid, block, 0, stream>>>(img, feats);
    }
    {
        dim3 grid(HS, BATCH);                      // 48 x 16 = 768 blocks, 3/CU
        dim3 block(12, 48);                        // 576 threads = 9 waves
        row_affinity_kernel<<<grid, block, 0, stream>>>(feats, out4);
    }
}